// Round 3
// baseline (2534.897 us; speedup 1.0000x reference)
//
#include <hip/hip_runtime.h>
#include <hip/hip_bf16.h>

typedef __bf16 bf16x8 __attribute__((ext_vector_type(8)));
typedef float f32x4 __attribute__((ext_vector_type(4)));
typedef short short8 __attribute__((ext_vector_type(8)));
typedef short short4v __attribute__((ext_vector_type(4)));

// LDS layout (units: shorts/bf16)
//   q_s : 64 x 264            @ 0        (reused as o_s in phase 3/4)
//   k_s : 64 x 264            @ 16896
//   x_s : 64 x 264 (phase0-1) @ 33792  -- overlaid by vT[256][72] (phase1+)
//   p_s : 8 waves x 16 x 72   @ 52224
// total 61440 shorts = 122880 B
#define OFF_Q 0
#define OFF_K 16896
#define OFF_XV 33792
#define OFF_P 52224
#define STRIDE 264
#define VSTRIDE 72
#define PSTRIDE 72

__device__ __forceinline__ float b2f(short s) {
  unsigned u = ((unsigned)(unsigned short)s) << 16;
  float f; __builtin_memcpy(&f, &u, 4); return f;
}
__device__ __forceinline__ short f2b(float f) {
  unsigned u; __builtin_memcpy(&u, &f, 4);
  u += 0x7FFFu + ((u >> 16) & 1u);
  return (short)(u >> 16);
}
__device__ __forceinline__ bf16x8 ld8(const short* p) {
  short8 s = *(const short8*)p;
  bf16x8 f; __builtin_memcpy(&f, &s, 16); return f;
}
// load 8 logical elements starting at element index i; f32!=0 -> fp32 data
__device__ __forceinline__ bf16x8 ld8auto(const void* p, size_t i, int f32) {
  if (f32) {
    const float* fp = (const float*)p + i;
    f32x4 a = *(const f32x4*)fp;
    f32x4 b2 = *(const f32x4*)(fp + 4);
    short8 s;
    s[0] = f2b(a[0]); s[1] = f2b(a[1]); s[2] = f2b(a[2]); s[3] = f2b(a[3]);
    s[4] = f2b(b2[0]); s[5] = f2b(b2[1]); s[6] = f2b(b2[2]); s[7] = f2b(b2[3]);
    bf16x8 r; __builtin_memcpy(&r, &s, 16); return r;
  }
  return ld8((const short*)p + i);
}
__device__ __forceinline__ float ldE(const void* p, size_t i, int f32) {
  return f32 ? ((const float*)p)[i] : b2f(((const short*)p)[i]);
}
__device__ __forceinline__ f32x4 mfma16(bf16x8 a, bf16x8 b, f32x4 c) {
  return __builtin_amdgcn_mfma_f32_16x16x32_bf16(a, b, c, 0, 0, 0);
}

// ---- dtype detector: block b scans input b's even-index shorts.
// fp32 data: even shorts = low mantissa halves -> random exponents -> max ~255
// bf16 N(0,1) data: exponent <= ~130.  flag = (maxExp >= 160)
__global__ __launch_bounds__(256) void detect_k(
    const short* p0, int n0, const short* p1, int n1, const short* p2, int n2,
    const short* p3, int n3, const short* p4, int n4, const short* p5, int n5,
    const short* p6, int n6, int* flags)
{
  const short* ps[7] = {p0, p1, p2, p3, p4, p5, p6};
  int ns[7] = {n0, n1, n2, n3, n4, n5, n6};
  int b = blockIdx.x;
  const short* p = ps[b];
  int n = ns[b];
  __shared__ int mx;
  if (threadIdx.x == 0) mx = 0;
  __syncthreads();
  int K = n >> 1; if (K > 4096) K = 4096;
  int lm = 0;
  for (int k = threadIdx.x; k < K; k += 256) {
    int e = (((int)(unsigned short)p[2 * k]) >> 7) & 0xFF;
    lm = lm > e ? lm : e;
  }
  atomicMax(&mx, lm);
  __syncthreads();
  if (threadIdx.x == 0) flags[b] = (mx >= 160) ? 1 : 0;
}

__global__ __launch_bounds__(512, 2) void wmsa(
    const void* __restrict__ xg, const void* __restrict__ maskg,
    const void* __restrict__ qkvw, const void* __restrict__ qkvb,
    const void* __restrict__ projw, const void* __restrict__ projb,
    const void* __restrict__ btab, void* __restrict__ outg,
    const int* __restrict__ flags)
{
  __shared__ __align__(16) short lds[61440];
  const int tid  = threadIdx.x;
  const int w    = tid >> 6;
  const int lane = tid & 63;
  const int L    = lane & 15;
  const int quad = lane >> 4;
  const int b    = blockIdx.x;

  const int fx  = flags[0], fm = flags[1], fqw = flags[2], fqb = flags[3];
  const int fpw = flags[4], fpb = flags[5], fbt = flags[6];

  short* q_s = lds + OFF_Q;
  short* k_s = lds + OFF_K;
  short* x_s = lds + OFF_XV;
  short* vT  = lds + OFF_XV;
  short* p_w = lds + OFF_P + w * 16 * PSTRIDE;
  short* o_s = lds + OFF_Q;

  // ---------------- phase 0: stage x -> LDS bf16, zero pad rows 49..63
  if (fx) {
    const float* xb = (const float*)xg + (size_t)b * (49 * 256);
    for (int i = tid; i < 1568; i += 512) {
      int t = i >> 5, c8 = i & 31;
      const float* s = xb + t * 256 + c8 * 8;
      f32x4 a = *(const f32x4*)s;
      f32x4 c = *(const f32x4*)(s + 4);
      short8 v;
      v[0] = f2b(a[0]); v[1] = f2b(a[1]); v[2] = f2b(a[2]); v[3] = f2b(a[3]);
      v[4] = f2b(c[0]); v[5] = f2b(c[1]); v[6] = f2b(c[2]); v[7] = f2b(c[3]);
      *(short8*)(x_s + t * STRIDE + c8 * 8) = v;
    }
  } else {
    const short* xb = (const short*)xg + (size_t)b * (49 * 256);
    for (int i = tid; i < 1568; i += 512) {
      int t = i >> 5, c8 = i & 31;
      *(short8*)(x_s + t * STRIDE + c8 * 8) = *(const short8*)(xb + t * 256 + c8 * 8);
    }
  }
  for (int i = tid; i < 495; i += 512) {
    int t = 49 + i / 33, c8 = i - (i / 33) * 33;
    *(short8*)(x_s + t * STRIDE + c8 * 8) = short8{0,0,0,0,0,0,0,0};
  }
  __syncthreads();  // barrier 1: x staged

  const int mb   = w & 3;
  const int half = w >> 2;

  // ---------------- phase 1: QKV = x @ qkv_w^T (+b)
  bf16x8 afr[8];
  {
    const short* ar = x_s + (mb * 16 + L) * STRIDE + quad * 8;
    #pragma unroll
    for (int ks = 0; ks < 8; ks++) afr[ks] = ld8(ar + ks * 32);
  }
  __syncthreads();  // barrier 2: x reads done, vT may overlay

  {
    const float scale = 0.17677669529663687f;  // 32^-0.5
    int nb = half * 24;
    bf16x8 cur[8];
    {
      size_t base = (size_t)(nb * 16 + L) * 256 + quad * 8;
      #pragma unroll
      for (int ks = 0; ks < 8; ks++) cur[ks] = ld8auto(qkvw, base + ks * 32, fqw);
    }
    for (int i = 0; i < 24; i++, nb++) {
      bf16x8 nxt[8];
      if (i < 23) {
        size_t base = (size_t)((nb + 1) * 16 + L) * 256 + quad * 8;
        #pragma unroll
        for (int ks = 0; ks < 8; ks++) nxt[ks] = ld8auto(qkvw, base + ks * 32, fqw);
      }
      f32x4 acc = {0.f, 0.f, 0.f, 0.f};
      #pragma unroll
      for (int ks = 0; ks < 8; ks++) acc = mfma16(afr[ks], cur[ks], acc);
      float bias = ldE(qkvb, nb * 16 + L, fqb);
      int trow = mb * 16 + quad * 4;
      if (nb < 16) {            // Q: apply softmax scale
        #pragma unroll
        for (int r = 0; r < 4; r++)
          q_s[(trow + r) * STRIDE + nb * 16 + L] = f2b((acc[r] + bias) * scale);
      } else if (nb < 32) {     // K
        #pragma unroll
        for (int r = 0; r < 4; r++)
          k_s[(trow + r) * STRIDE + (nb - 16) * 16 + L] = f2b(acc[r] + bias);
      } else {                  // V, stored transposed [c][t]
        int col = (nb - 32) * 16 + L;
        #pragma unroll
        for (int r = 0; r < 4; r++)
          vT[col * VSTRIDE + trow + r] = f2b(acc[r] + bias);
      }
      #pragma unroll
      for (int ks = 0; ks < 8; ks++) cur[ks] = nxt[ks];
    }
  }
  __syncthreads();  // barrier 3: q_s/k_s/vT complete

  // ---------------- phase 2+3: per-head attention (wave = head), S^T trick
  const int h = w;
  float oacc[4][2][4];
  {
    bf16x8 fk[4];
    #pragma unroll
    for (int m = 0; m < 4; m++)
      fk[m] = ld8(k_s + (m * 16 + L) * STRIDE + h * 32 + quad * 8);
    const int widx = b & 63;
    #pragma unroll
    for (int nbq = 0; nbq < 4; nbq++) {
      int tq  = nbq * 16 + L;
      int tqc = tq < 49 ? tq : 48;
      int qr = tqc / 7, qc = tqc - qr * 7;
      bf16x8 fq = ld8(q_s + tq * STRIDE + h * 32 + quad * 8);
      f32x4 s[4];
      #pragma unroll
      for (int m = 0; m < 4; m++) {
        f32x4 z = {0.f, 0.f, 0.f, 0.f};
        s[m] = mfma16(fk[m], fq, z);           // S^T tile: rows tk, cols tq
      }
      float vals[16];
      float mx = -1e30f;
      #pragma unroll
      for (int m = 0; m < 4; m++) {
        #pragma unroll
        for (int r = 0; r < 4; r++) {
          int tk = m * 16 + quad * 4 + r;
          float v = -1e30f;
          if (tk < 49) {
            int kr = tk / 7, kc = tk - kr * 7;
            int idx = (qr - kr + 6) * 13 + (qc - kc + 6);
            v = s[m][r] + ldE(btab, (size_t)idx * 8 + h, fbt)
                        + ldE(maskg, (size_t)widx * 2401 + tqc * 49 + tk, fm);
          }
          vals[m * 4 + r] = v;
          mx = fmaxf(mx, v);
        }
      }
      mx = fmaxf(mx, __shfl_xor(mx, 16));
      mx = fmaxf(mx, __shfl_xor(mx, 32));
      float sum = 0.f;
      #pragma unroll
      for (int i2 = 0; i2 < 16; i2++) { vals[i2] = __expf(vals[i2] - mx); sum += vals[i2]; }
      sum += __shfl_xor(sum, 16);
      sum += __shfl_xor(sum, 32);
      float inv = 1.f / sum;
      #pragma unroll
      for (int m = 0; m < 4; m++) {            // P -> bf16, C-layout -> A-layout via LDS
        short4v pk;
        #pragma unroll
        for (int r = 0; r < 4; r++) pk[r] = f2b(vals[m * 4 + r] * inv);
        *(short4v*)(p_w + L * PSTRIDE + m * 16 + quad * 4) = pk;
      }
      asm volatile("" ::: "memory");
      f32x4 o0 = {0.f,0.f,0.f,0.f}, o1 = {0.f,0.f,0.f,0.f};
      #pragma unroll
      for (int ks2 = 0; ks2 < 2; ks2++) {
        bf16x8 fp  = ld8(p_w + L * PSTRIDE + ks2 * 32 + quad * 8);
        bf16x8 fv0 = ld8(vT + (h * 32 + L) * VSTRIDE + ks2 * 32 + quad * 8);
        bf16x8 fv1 = ld8(vT + (h * 32 + 16 + L) * VSTRIDE + ks2 * 32 + quad * 8);
        o0 = mfma16(fp, fv0, o0);
        o1 = mfma16(fp, fv1, o1);
      }
      asm volatile("" ::: "memory");
      #pragma unroll
      for (int r = 0; r < 4; r++) { oacc[nbq][0][r] = o0[r]; oacc[nbq][1][r] = o1[r]; }
    }
  }
  __syncthreads();  // barrier 4
  #pragma unroll
  for (int nbq = 0; nbq < 4; nbq++)
    #pragma unroll
    for (int nbd = 0; nbd < 2; nbd++)
      #pragma unroll
      for (int r = 0; r < 4; r++)
        o_s[(nbq * 16 + quad * 4 + r) * STRIDE + h * 32 + nbd * 16 + L] =
            f2b(oacc[nbq][nbd][r]);
  __syncthreads();  // barrier 5: o_s complete

  // ---------------- phase 4: out = o @ proj_w^T + proj_b
  {
    bf16x8 ao[8];
    const short* orow = o_s + (mb * 16 + L) * STRIDE + quad * 8;
    #pragma unroll
    for (int ks = 0; ks < 8; ks++) ao[ks] = ld8(orow + ks * 32);
    int nb = half * 8;
    bf16x8 cur[8];
    {
      size_t base = (size_t)(nb * 16 + L) * 256 + quad * 8;
      #pragma unroll
      for (int ks = 0; ks < 8; ks++) cur[ks] = ld8auto(projw, base + ks * 32, fpw);
    }
    for (int i = 0; i < 8; i++, nb++) {
      bf16x8 nxt[8];
      if (i < 7) {
        size_t base = (size_t)((nb + 1) * 16 + L) * 256 + quad * 8;
        #pragma unroll
        for (int ks = 0; ks < 8; ks++) nxt[ks] = ld8auto(projw, base + ks * 32, fpw);
      }
      f32x4 acc = {0.f, 0.f, 0.f, 0.f};
      #pragma unroll
      for (int ks = 0; ks < 8; ks++) acc = mfma16(ao[ks], cur[ks], acc);
      float bias = ldE(projb, nb * 16 + L, fpb);
      #pragma unroll
      for (int r = 0; r < 4; r++) {
        int t = mb * 16 + quad * 4 + r;
        if (t < 49) {
          size_t ofs = (size_t)b * (49 * 256) + t * 256 + nb * 16 + L;
          float val = acc[r] + bias;
          if (fx) ((float*)outg)[ofs] = val;
          else    ((short*)outg)[ofs] = f2b(val);
        }
      }
      #pragma unroll
      for (int ks = 0; ks < 8; ks++) cur[ks] = nxt[ks];
    }
  }
}

extern "C" void kernel_launch(void* const* d_in, const int* in_sizes, int n_in,
                              void* d_out, int out_size, void* d_ws, size_t ws_size,
                              hipStream_t stream) {
  (void)n_in; (void)out_size; (void)ws_size;
  int B = in_sizes[0] / (49 * 256);  // 4096
  int* flags = (int*)d_ws;
  detect_k<<<7, 256, 0, stream>>>(
      (const short*)d_in[0], in_sizes[0], (const short*)d_in[1], in_sizes[1],
      (const short*)d_in[2], in_sizes[2], (const short*)d_in[3], in_sizes[3],
      (const short*)d_in[4], in_sizes[4], (const short*)d_in[5], in_sizes[5],
      (const short*)d_in[6], in_sizes[6], flags);
  wmsa<<<B, 512, 0, stream>>>(
      d_in[0], d_in[1], d_in[2], d_in[3], d_in[4], d_in[5], d_in[6],
      d_out, flags);
}